// Round 6
// baseline (124.135 us; speedup 1.0000x reference)
//
#include <hip/hip_runtime.h>
#include <hip/hip_bf16.h>
#include <cstdio>

#define T_DIM 2048
#define B_DIM 2
#define E_DIM 1024
#define H_DIM 16
#define S_DIM 64
#define LOG2E 1.44269504088896340736f

typedef __attribute__((ext_vector_type(4))) float f32x4;
typedef __attribute__((ext_vector_type(16))) float f32x16;
typedef __attribute__((ext_vector_type(8))) short bf16x8;
typedef __attribute__((ext_vector_type(8))) unsigned short u16x8;
typedef __attribute__((ext_vector_type(4))) unsigned short u16x4;

#define MFMA16(a,b,c) __builtin_amdgcn_mfma_f32_16x16x32_bf16((a),(b),(c),0,0,0)
#define MFMA32(a,b,c) __builtin_amdgcn_mfma_f32_32x32x16_bf16((a),(b),(c),0,0,0)

__device__ __forceinline__ unsigned short f2bf(float f) {
    union { __hip_bfloat16 h; unsigned short u; } c;
    c.h = __float2bfloat16(f);
    return c.u;
}
__device__ __forceinline__ float bf2f(unsigned short u) {
    union { __hip_bfloat16 h; unsigned short u; } c;
    c.u = u;
    return __bfloat162float(c.h);
}
__device__ __forceinline__ f32x16 zero16() {
    f32x16 v;
#pragma unroll
    for (int i = 0; i < 16; ++i) v[i] = 0.f;
    return v;
}

// ---------------- Kernel 0: weight prep (split Wq/Wk/Wv hi/lo + Wr->bf16) ----
// blocks [0,768): one elem each of the 3*65536 QKV weights -> hi/lo split.
// blocks [768,1792): 4 elems each of Wr (1M) -> bf16.
__global__ __launch_bounds__(256) void prep_w(
    const float* __restrict__ Wq, const float* __restrict__ Wk,
    const float* __restrict__ Wv, const float* __restrict__ Wr,
    unsigned short* __restrict__ whi, unsigned short* __restrict__ wlo,
    unsigned short* __restrict__ wrb)
{
    int bid = blockIdx.x;
    if (bid < 768) {
        int i = bid * 256 + threadIdx.x;   // < 196608
        const float* src = (i < 65536) ? Wq : ((i < 131072) ? Wk : Wv);
        float v = src[i & 65535];
        unsigned short h = f2bf(v);
        whi[i] = h;
        wlo[i] = f2bf(v - bf2f(h));
    } else {
        int i = (bid - 768) * 256 + threadIdx.x;   // < 262144
        float4 v = reinterpret_cast<const float4*>(Wr)[i];
        u16x4 o;
        o[0] = f2bf(v.x); o[1] = f2bf(v.y); o[2] = f2bf(v.z); o[3] = f2bf(v.w);
        *reinterpret_cast<u16x4*>(wrb + (size_t)i * 4) = o;
    }
}

// ---------------- Kernel 1: QKV projection via hi/lo bf16 MFMA ----------------
// fp32-grade: acc = xh*wh + xl*wh + xh*wl. One wave per block; 32 t x 32 d x 3.
__global__ __launch_bounds__(64) void qkv_mfma(
    const float* __restrict__ x, const unsigned short* __restrict__ whi,
    const unsigned short* __restrict__ wlo, const float* __restrict__ Er,
    unsigned short* __restrict__ qh_g, unsigned short* __restrict__ ql_g,
    unsigned short* __restrict__ kh_g, unsigned short* __restrict__ vT_g)
{
    int bid = blockIdx.x;
    int dg = bid & 1;
    int tt = (bid >> 1) & 63;
    int h  = (bid >> 7) & 15;
    int b  = bid >> 11;
    int bh = b * H_DIM + h;
    int t0 = tt * 32;
    int lane = threadIdx.x;
    int l31 = lane & 31, hs = lane >> 5;

    // x row fragments, split hi/lo (lane: row t0+l31, k-chunk hs*8)
    bf16x8 xh[4], xl[4];
    const float* xrow = x + (size_t)(t0 + l31) * (B_DIM * E_DIM) + (size_t)b * E_DIM + h * 64;
#pragma unroll
    for (int ks = 0; ks < 4; ++ks) {
        float vv[8];
        *reinterpret_cast<float4*>(&vv[0]) = *reinterpret_cast<const float4*>(xrow + ks * 16 + hs * 8);
        *reinterpret_cast<float4*>(&vv[4]) = *reinterpret_cast<const float4*>(xrow + ks * 16 + hs * 8 + 4);
        unsigned short hh[8], ll[8];
#pragma unroll
        for (int j = 0; j < 8; ++j) {
            hh[j] = f2bf(vv[j]);
            ll[j] = f2bf(vv[j] - bf2f(hh[j]));
        }
        xh[ks] = *reinterpret_cast<bf16x8*>(hh);
        xl[ks] = *reinterpret_cast<bf16x8*>(ll);
    }

    f32x16 aq = zero16(), ak = zero16(), av = zero16();
    size_t wofs = (size_t)h * 4096 + (size_t)(dg * 32 + l31) * 64 + hs * 8;
    const unsigned short* whp = whi + wofs;
    const unsigned short* wlp = wlo + wofs;
#pragma unroll
    for (int ks = 0; ks < 4; ++ks) {
        bf16x8 qwh = *reinterpret_cast<const bf16x8*>(whp + ks * 16);
        bf16x8 qwl = *reinterpret_cast<const bf16x8*>(wlp + ks * 16);
        bf16x8 kwh = *reinterpret_cast<const bf16x8*>(whp + 65536 + ks * 16);
        bf16x8 kwl = *reinterpret_cast<const bf16x8*>(wlp + 65536 + ks * 16);
        bf16x8 vwh = *reinterpret_cast<const bf16x8*>(whp + 131072 + ks * 16);
        bf16x8 vwl = *reinterpret_cast<const bf16x8*>(wlp + 131072 + ks * 16);
        aq = MFMA32(xh[ks], qwh, aq);
        aq = MFMA32(xl[ks], qwh, aq);
        aq = MFMA32(xh[ks], qwl, aq);
        ak = MFMA32(xh[ks], kwh, ak);
        ak = MFMA32(xl[ks], kwh, ak);
        ak = MFMA32(xh[ks], kwl, ak);
        av = MFMA32(vwh, xh[ks], av);   // v computed transposed: D = W*x^T
        av = MFMA32(vwh, xl[ks], av);
        av = MFMA32(vwl, xh[ks], av);
    }

    // epilogue: q hi/lo, k' (srel+scale+log2e folded, Er read directly), vT
    size_t rowbase = (size_t)bh * T_DIM * 64;
#pragma unroll
    for (int r = 0; r < 16; ++r) {
        int rowp = (r & 3) + 8 * (r >> 2) + 4 * hs;
        int t = t0 + rowp;
        int d = dg * 32 + l31;
        size_t ro = rowbase + (size_t)t * 64 + d;
        float qv = aq[r];
        unsigned short qhi = f2bf(qv);
        qh_g[ro] = qhi;
        ql_g[ro] = f2bf(qv - bf2f(qhi));
        float kv = (ak[r] * 0.03125f + Er[(size_t)d * T_DIM + t]) * LOG2E;
        kh_g[ro] = f2bf(kv);
        // av frag: col = t (t0+l31), row = d (dg*32+rowp)
        vT_g[((size_t)bh * 64 + dg * 32 + rowp) * T_DIM + t0 + l31] = f2bf(av[r]);
    }
}

// ---------------- Kernel 2: causal flash attention, barrier-free -------------
// 1 wave per block (32 q-rows). K/V read global->VGPR (L2-resident per XCD),
// 1-step register prefetch, zero LDS staging, zero barriers. Swapped QK^T ->
// lane-local softmax with defer-max; PV as O^T = V^T x P^T; P in-register.
struct KVfrag { bf16x8 k0, k1, k2, k3, v0, v1, v2, v3; };

__global__ __launch_bounds__(64) void attn_flash(
    const unsigned short* __restrict__ qh_g, const unsigned short* __restrict__ ql_g,
    const unsigned short* __restrict__ kh_g, const unsigned short* __restrict__ vT_g,
    unsigned short* __restrict__ attT)
{
    __shared__ __align__(16) unsigned short OT[64 * 40];   // [d][q+pad] epilogue only

    int bid = blockIdx.x;
    // bid%8 = bh>>2 -> each XCD owns 4 heads (2MB K+V, L2-resident).
    int bh = ((bid & 7) << 2) | ((bid >> 3) & 3);
    // qt bijection: every CU's 8 resident waves sum to 260 k-steps, heavy first.
    int u = bid >> 5;
    int s8 = u >> 3, a = s8 >> 1, r7 = u & 7;
    int qt = (s8 & 1) ? (a * 8 + r7) : (63 - a * 8 - r7);

    int lane = threadIdx.x;
    int l31 = lane & 31, hs = lane >> 5;

    size_t base = (size_t)bh * T_DIM * 64;

    // Q fragments (held for the whole wave): q-row = qt*32 + l31
    bf16x8 qBh[4], qBl[4];
    {
        size_t qoff = base + (size_t)(qt * 32 + l31) * 64 + hs * 8;
#pragma unroll
        for (int st = 0; st < 4; ++st) {
            qBh[st] = *reinterpret_cast<const bf16x8*>(qh_g + qoff + st * 16);
            qBl[st] = *reinterpret_cast<const bf16x8*>(ql_g + qoff + st * 16);
        }
    }

    f32x16 oacc0 = zero16(), oacc1 = zero16();   // O^T: col=q(lane), regs=d
    float m = -1e30f, lsum = 0.f;

    const unsigned short* kp = kh_g + base + (size_t)l31 * 64 + hs * 8;
    const unsigned short* vp = vT_g + base + (size_t)l31 * T_DIM + hs * 8;

    auto loadKV = [&](KVfrag& f, int kt) {
        const unsigned short* k = kp + (size_t)kt * 2048;
        f.k0 = *reinterpret_cast<const bf16x8*>(k);
        f.k1 = *reinterpret_cast<const bf16x8*>(k + 16);
        f.k2 = *reinterpret_cast<const bf16x8*>(k + 32);
        f.k3 = *reinterpret_cast<const bf16x8*>(k + 48);
        const unsigned short* v = vp + kt * 32;
        f.v0 = *reinterpret_cast<const bf16x8*>(v);                        // dt0 half0
        f.v1 = *reinterpret_cast<const bf16x8*>(v + 16);                   // dt0 half1
        f.v2 = *reinterpret_cast<const bf16x8*>(v + (size_t)32 * T_DIM);   // dt1 half0
        f.v3 = *reinterpret_cast<const bf16x8*>(v + (size_t)32 * T_DIM + 16);
    };

    auto computeStep = [&](const KVfrag& f, bool diag) {
        // ---- S^T = K' x Q (hi + lo): col=q=l31, regs=krow ----
        f32x16 s = zero16();
        s = MFMA32(f.k0, qBh[0], s); s = MFMA32(f.k0, qBl[0], s);
        s = MFMA32(f.k1, qBh[1], s); s = MFMA32(f.k1, qBl[1], s);
        s = MFMA32(f.k2, qBh[2], s); s = MFMA32(f.k2, qBl[2], s);
        s = MFMA32(f.k3, qBh[3], s); s = MFMA32(f.k3, qBl[3], s);
        if (diag) {
#pragma unroll
            for (int r = 0; r < 16; ++r) {
                int rowp = (r & 3) + 8 * (r >> 2) + 4 * hs;
                if (rowp > l31) s[r] = -1e30f;   // mask krow > q
            }
        }
        // ---- online softmax, defer-max (THR=8 in log2 domain -> p<=256) ----
        float h0 = fmaxf(fmaxf(s[0], s[1]), s[2]);
        h0 = fmaxf(fmaxf(h0, s[3]), s[4]);
        h0 = fmaxf(fmaxf(h0, s[5]), s[6]);
        float h1 = fmaxf(fmaxf(s[8], s[9]), s[10]);
        h1 = fmaxf(fmaxf(h1, s[11]), s[12]);
        h1 = fmaxf(fmaxf(h1, s[13]), s[14]);
        float pmax = fmaxf(fmaxf(h0, s[7]), fmaxf(h1, s[15]));
        pmax = fmaxf(pmax, __shfl_xor(pmax, 32));
        if (__ballot(pmax > m + 8.f)) {
            float mn = fmaxf(m, pmax);
            float sc = __builtin_amdgcn_exp2f(m - mn);
            m = mn; lsum *= sc;
#pragma unroll
            for (int r = 0; r < 16; ++r) { oacc0[r] *= sc; oacc1[r] *= sc; }
        }
        float p[16], psum = 0.f;
#pragma unroll
        for (int r = 0; r < 16; ++r) {
            p[r] = __builtin_amdgcn_exp2f(s[r] - m);
            psum += p[r];
        }
        lsum += psum + __shfl_xor(psum, 32);

        // ---- P -> bf16 PV B-frags in-register (cvt_pk + permlane32_swap) ----
        unsigned int wp[8];
#pragma unroll
        for (int q2 = 0; q2 < 2; ++q2) {
            int o = q2 * 8, d2 = q2 * 4;
            asm("v_cvt_pk_bf16_f32 %0, %1, %2" : "=v"(wp[d2+0]) : "v"(p[o+0]), "v"(p[o+1]));
            asm("v_cvt_pk_bf16_f32 %0, %1, %2" : "=v"(wp[d2+1]) : "v"(p[o+2]), "v"(p[o+3]));
            asm("v_cvt_pk_bf16_f32 %0, %1, %2" : "=v"(wp[d2+2]) : "v"(p[o+4]), "v"(p[o+5]));
            asm("v_cvt_pk_bf16_f32 %0, %1, %2" : "=v"(wp[d2+3]) : "v"(p[o+6]), "v"(p[o+7]));
            asm("v_permlane32_swap_b32 %0, %1" : "+v"(wp[d2+0]), "+v"(wp[d2+2]));
            asm("v_permlane32_swap_b32 %0, %1" : "+v"(wp[d2+1]), "+v"(wp[d2+3]));
        }
        // ---- PV: O^T += V^T x P^T ----
        union { unsigned int u[4]; bf16x8 v; } pa0, pa1;
        pa0.u[0] = wp[0]; pa0.u[1] = wp[1]; pa0.u[2] = wp[2]; pa0.u[3] = wp[3];
        pa1.u[0] = wp[4]; pa1.u[1] = wp[5]; pa1.u[2] = wp[6]; pa1.u[3] = wp[7];
        oacc0 = MFMA32(f.v0, pa0.v, oacc0);
        oacc0 = MFMA32(f.v1, pa1.v, oacc0);
        oacc1 = MFMA32(f.v2, pa0.v, oacc1);
        oacc1 = MFMA32(f.v3, pa1.v, oacc1);
    };

    int nkt = qt + 1;
    KVfrag A, Bf;
    loadKV(A, 0);
    for (int kt = 0; kt < nkt; kt += 2) {
        if (kt + 1 < nkt) loadKV(Bf, kt + 1);      // prefetch (indep of A use)
        computeStep(A, kt == nkt - 1);
        if (kt + 1 < nkt) {
            if (kt + 2 < nkt) loadKV(A, kt + 2);   // prefetch next-next
            computeStep(Bf, kt + 1 == nkt - 1);
        }
    }

    // ---- epilogue: normalize (lane-local), transpose via per-wave LDS ----
    float inv = 1.f / lsum;
#pragma unroll
    for (int r = 0; r < 16; ++r) {
        int rowp = (r & 3) + 8 * (r >> 2) + 4 * hs;   // d-row within 32
        OT[rowp * 40 + l31]        = f2bf(oacc0[r] * inv);
        OT[(32 + rowp) * 40 + l31] = f2bf(oacc1[r] * inv);
    }
    // same-wave LDS RAW: compiler emits lgkmcnt wait (array-level aliasing)
    unsigned short* dst = attT + ((size_t)bh * 64 + lane) * T_DIM + qt * 32;
    *reinterpret_cast<u16x8*>(dst)      = *reinterpret_cast<const u16x8*>(&OT[lane * 40]);
    *reinterpret_cast<u16x8*>(dst + 8)  = *reinterpret_cast<const u16x8*>(&OT[lane * 40 + 8]);
    *reinterpret_cast<u16x8*>(dst + 16) = *reinterpret_cast<const u16x8*>(&OT[lane * 40 + 16]);
    *reinterpret_cast<u16x8*>(dst + 24) = *reinterpret_cast<const u16x8*>(&OT[lane * 40 + 24]);
}

// ---------------- Kernel 3: out = attT(as [4096][1024]) @ Wr^T + br ----------
// Register-staged async prefetch: issue loads(kt+1) before compute(kt).
__global__ __launch_bounds__(256) void final_gemm_mfma(
    const unsigned short* __restrict__ A, const unsigned short* __restrict__ Bw,
    const float* __restrict__ br, float* __restrict__ out)
{
    __shared__ __align__(16) unsigned short gsm[9216];
    int nt = blockIdx.x;
    int mt = blockIdx.y;
    int tid = threadIdx.x;
    int w = tid >> 6;
    int lane = tid & 63;
    int l15 = lane & 15;
    int l4 = lane >> 4;
    int ch = tid & 7;

    f32x4 acc[4];
#pragma unroll
    for (int n = 0; n < 4; ++n) acc[n] = (f32x4){0.f, 0.f, 0.f, 0.f};

    u16x8 rr[4];
#pragma unroll
    for (int k2 = 0; k2 < 4; ++k2) {
        int row = ((tid >> 3) + 32 * k2) & 63;
        const unsigned short* src = (k2 >= 2)
            ? Bw + (size_t)(nt * 64 + row) * 1024 + ch * 8
            : A  + (size_t)(mt * 64 + row) * 1024 + ch * 8;
        rr[k2] = *reinterpret_cast<const u16x8*>(src);
    }

#pragma unroll
    for (int kt = 0; kt < 16; ++kt) {
#pragma unroll
        for (int k2 = 0; k2 < 4; ++k2) {
            int row = ((tid >> 3) + 32 * k2) & 63;
            *reinterpret_cast<u16x8*>(&gsm[(k2 >> 1) * 4608 + row * 72 + ch * 8]) = rr[k2];
        }
        __syncthreads();
        u16x8 rnext[4];
        if (kt < 15) {
#pragma unroll
            for (int k2 = 0; k2 < 4; ++k2) {
                int row = ((tid >> 3) + 32 * k2) & 63;
                const unsigned short* src = (k2 >= 2)
                    ? Bw + (size_t)(nt * 64 + row) * 1024 + (kt + 1) * 64 + ch * 8
                    : A  + (size_t)(mt * 64 + row) * 1024 + (kt + 1) * 64 + ch * 8;
                rnext[k2] = *reinterpret_cast<const u16x8*>(src);
            }
        }
        bf16x8 a0 = *reinterpret_cast<const bf16x8*>(&gsm[(w * 16 + l15) * 72 + l4 * 8]);
        bf16x8 a1 = *reinterpret_cast<const bf16x8*>(&gsm[(w * 16 + l15) * 72 + 32 + l4 * 8]);
#pragma unroll
        for (int n = 0; n < 4; ++n) {
            bf16x8 b0 = *reinterpret_cast<const bf16x8*>(&gsm[4608 + (n * 16 + l15) * 72 + l4 * 8]);
            bf16x8 b1 = *reinterpret_cast<const bf16x8*>(&gsm[4608 + (n * 16 + l15) * 72 + 32 + l4 * 8]);
            acc[n] = MFMA16(a0, b0, acc[n]);
            acc[n] = MFMA16(a1, b1, acc[n]);
        }
        __syncthreads();
#pragma unroll
        for (int k2 = 0; k2 < 4; ++k2) rr[k2] = rnext[k2];
    }

#pragma unroll
    for (int n = 0; n < 4; ++n) {
        int col = nt * 64 + n * 16 + l15;
        float bias = br[col];
#pragma unroll
        for (int r = 0; r < 4; ++r) {
            int row = mt * 64 + w * 16 + l4 * 4 + r;
            out[(size_t)row * 1024 + col] = acc[n][r] + bias;
        }
    }
}

extern "C" void kernel_launch(void* const* d_in, const int* in_sizes, int n_in,
                              void* d_out, int out_size, void* d_ws, size_t ws_size,
                              hipStream_t stream) {
    const float* x  = (const float*)d_in[0];
    const float* Wq = (const float*)d_in[1];
    const float* Wk = (const float*)d_in[2];
    const float* Wv = (const float*)d_in[3];
    const float* Er = (const float*)d_in[4];
    const float* Wr = (const float*)d_in[5];
    const float* br = (const float*)d_in[6];
    float* out = (float*)d_out;

    const size_t nQ = (size_t)B_DIM * H_DIM * T_DIM * S_DIM;   // 4,194,304
    char* p = (char*)d_ws;
    unsigned short* qh = (unsigned short*)p;   p += nQ * 2;
    unsigned short* ql = (unsigned short*)p;   p += nQ * 2;
    unsigned short* kh = (unsigned short*)p;   p += nQ * 2;
    unsigned short* vT = (unsigned short*)p;   p += nQ * 2;
    unsigned short* attT = (unsigned short*)p; p += nQ * 2;
    unsigned short* wrb = (unsigned short*)p;  p += (size_t)E_DIM * E_DIM * 2;
    unsigned short* whi = (unsigned short*)p;  p += (size_t)3 * 65536 * 2;
    unsigned short* wlo = (unsigned short*)p;  p += (size_t)3 * 65536 * 2;
    size_t need = (size_t)(p - (char*)d_ws);
    if (ws_size < need) {
        fprintf(stderr, "WS TOO SMALL: have %zu need %zu\n", ws_size, need);
        return;
    }

    prep_w<<<1792, 256, 0, stream>>>(Wq, Wk, Wv, Wr, whi, wlo, wrb);
    qkv_mfma<<<4096, 64, 0, stream>>>(x, whi, wlo, Er, qh, ql, kh, vT);
    attn_flash<<<2048, 64, 0, stream>>>(qh, ql, kh, vT, attT);
    final_gemm_mfma<<<dim3(16, 64), 256, 0, stream>>>(attT, wrb, br, out);
}

// Round 7
// 106.524 us; speedup vs baseline: 1.1653x; 1.1653x over previous
//
#include <hip/hip_runtime.h>
#include <hip/hip_bf16.h>
#include <cstdio>

#define T_DIM 2048
#define B_DIM 2
#define E_DIM 1024
#define H_DIM 16
#define S_DIM 64
#define LOG2E 1.44269504088896340736f

typedef __attribute__((ext_vector_type(4))) float f32x4;
typedef __attribute__((ext_vector_type(16))) float f32x16;
typedef __attribute__((ext_vector_type(8))) short bf16x8;
typedef __attribute__((ext_vector_type(8))) unsigned short u16x8;
typedef __attribute__((ext_vector_type(4))) unsigned short u16x4;

#define MFMA16(a,b,c) __builtin_amdgcn_mfma_f32_16x16x32_bf16((a),(b),(c),0,0,0)
#define MFMA32(a,b,c) __builtin_amdgcn_mfma_f32_32x32x16_bf16((a),(b),(c),0,0,0)

__device__ __forceinline__ unsigned short f2bf(float f) {
    union { __hip_bfloat16 h; unsigned short u; } c;
    c.h = __float2bfloat16(f);
    return c.u;
}
__device__ __forceinline__ float bf2f(unsigned short u) {
    union { __hip_bfloat16 h; unsigned short u; } c;
    c.u = u;
    return __bfloat162float(c.h);
}
__device__ __forceinline__ void gload16(const void* g, void* l) {
    __builtin_amdgcn_global_load_lds(
        (const __attribute__((address_space(1))) unsigned int*)g,
        (__attribute__((address_space(3))) unsigned int*)l, 16, 0, 0);
}
__device__ __forceinline__ f32x16 zero16() {
    f32x16 v;
#pragma unroll
    for (int i = 0; i < 16; ++i) v[i] = 0.f;
    return v;
}

// ---------------- Kernel 0: weight prep (split Wq/Wk/Wv hi/lo + Wr->bf16) ----
__global__ __launch_bounds__(256) void prep_w(
    const float* __restrict__ Wq, const float* __restrict__ Wk,
    const float* __restrict__ Wv, const float* __restrict__ Wr,
    unsigned short* __restrict__ whi, unsigned short* __restrict__ wlo,
    unsigned short* __restrict__ wrb)
{
    int bid = blockIdx.x;
    if (bid < 768) {
        int i = bid * 256 + threadIdx.x;   // < 196608
        const float* src = (i < 65536) ? Wq : ((i < 131072) ? Wk : Wv);
        float v = src[i & 65535];
        unsigned short h = f2bf(v);
        whi[i] = h;
        wlo[i] = f2bf(v - bf2f(h));
    } else {
        int i = (bid - 768) * 256 + threadIdx.x;   // < 262144
        float4 v = reinterpret_cast<const float4*>(Wr)[i];
        u16x4 o;
        o[0] = f2bf(v.x); o[1] = f2bf(v.y); o[2] = f2bf(v.z); o[3] = f2bf(v.w);
        *reinterpret_cast<u16x4*>(wrb + (size_t)i * 4) = o;
    }
}

// ---------------- Kernel 1: QKV projection via hi/lo bf16 MFMA ----------------
__global__ __launch_bounds__(64) void qkv_mfma(
    const float* __restrict__ x, const unsigned short* __restrict__ whi,
    const unsigned short* __restrict__ wlo, const float* __restrict__ Er,
    unsigned short* __restrict__ qh_g, unsigned short* __restrict__ ql_g,
    unsigned short* __restrict__ kh_g, unsigned short* __restrict__ vT_g)
{
    int bid = blockIdx.x;
    int dg = bid & 1;
    int tt = (bid >> 1) & 63;
    int h  = (bid >> 7) & 15;
    int b  = bid >> 11;
    int bh = b * H_DIM + h;
    int t0 = tt * 32;
    int lane = threadIdx.x;
    int l31 = lane & 31, hs = lane >> 5;

    bf16x8 xh[4], xl[4];
    const float* xrow = x + (size_t)(t0 + l31) * (B_DIM * E_DIM) + (size_t)b * E_DIM + h * 64;
#pragma unroll
    for (int ks = 0; ks < 4; ++ks) {
        float vv[8];
        *reinterpret_cast<float4*>(&vv[0]) = *reinterpret_cast<const float4*>(xrow + ks * 16 + hs * 8);
        *reinterpret_cast<float4*>(&vv[4]) = *reinterpret_cast<const float4*>(xrow + ks * 16 + hs * 8 + 4);
        unsigned short hh[8], ll[8];
#pragma unroll
        for (int j = 0; j < 8; ++j) {
            hh[j] = f2bf(vv[j]);
            ll[j] = f2bf(vv[j] - bf2f(hh[j]));
        }
        xh[ks] = *reinterpret_cast<bf16x8*>(hh);
        xl[ks] = *reinterpret_cast<bf16x8*>(ll);
    }

    f32x16 aq = zero16(), ak = zero16(), av = zero16();
    size_t wofs = (size_t)h * 4096 + (size_t)(dg * 32 + l31) * 64 + hs * 8;
    const unsigned short* whp = whi + wofs;
    const unsigned short* wlp = wlo + wofs;
#pragma unroll
    for (int ks = 0; ks < 4; ++ks) {
        bf16x8 qwh = *reinterpret_cast<const bf16x8*>(whp + ks * 16);
        bf16x8 qwl = *reinterpret_cast<const bf16x8*>(wlp + ks * 16);
        bf16x8 kwh = *reinterpret_cast<const bf16x8*>(whp + 65536 + ks * 16);
        bf16x8 kwl = *reinterpret_cast<const bf16x8*>(wlp + 65536 + ks * 16);
        bf16x8 vwh = *reinterpret_cast<const bf16x8*>(whp + 131072 + ks * 16);
        bf16x8 vwl = *reinterpret_cast<const bf16x8*>(wlp + 131072 + ks * 16);
        aq = MFMA32(xh[ks], qwh, aq);
        aq = MFMA32(xl[ks], qwh, aq);
        aq = MFMA32(xh[ks], qwl, aq);
        ak = MFMA32(xh[ks], kwh, ak);
        ak = MFMA32(xl[ks], kwh, ak);
        ak = MFMA32(xh[ks], kwl, ak);
        av = MFMA32(vwh, xh[ks], av);   // v computed transposed: D = W*x^T
        av = MFMA32(vwh, xl[ks], av);
        av = MFMA32(vwl, xh[ks], av);
    }

    size_t rowbase = (size_t)bh * T_DIM * 64;
#pragma unroll
    for (int r = 0; r < 16; ++r) {
        int rowp = (r & 3) + 8 * (r >> 2) + 4 * hs;
        int t = t0 + rowp;
        int d = dg * 32 + l31;
        size_t ro = rowbase + (size_t)t * 64 + d;
        float qv = aq[r];
        unsigned short qhi = f2bf(qv);
        qh_g[ro] = qhi;
        ql_g[ro] = f2bf(qv - bf2f(qhi));
        float kv = (ak[r] * 0.03125f + Er[(size_t)d * T_DIM + t]) * LOG2E;
        kh_g[ro] = f2bf(kv);
        vT_g[((size_t)bh * 64 + dg * 32 + rowp) * T_DIM + t0 + l31] = f2bf(av[r]);
    }
}

// ---------------- Kernel 2: causal flash attention, 32x32x16 MFMA ------------
// Round-5 structure (LDS-staged, dbuf prefetch) + 2-deep kt pipeline
// (QK(kt+1) issued before softmax(kt)+PV(kt)) + defer-max + setprio.
__global__ __launch_bounds__(256) void attn_mfma32(
    const unsigned short* __restrict__ qh_g, const unsigned short* __restrict__ ql_g,
    const unsigned short* __restrict__ kh_g, const unsigned short* __restrict__ vT_g,
    unsigned short* __restrict__ attT)
{
    __shared__ __align__(16) unsigned char smem[65536];
    float* OT = (float*)smem;   // [64][132] epilogue reuse

    int bid = blockIdx.x;
    int bh = bid & 31;            // all 16 blocks of a head -> same XCD (L2 reuse)
    int u = bid >> 5;
    int qt = (u < 8) ? (15 - u) : (u - 8);  // heavy first; pairs sum constant

    int tid = threadIdx.x;
    int w = tid >> 6;
    int lane = tid & 63;
    int l31 = lane & 31;
    int hs = lane >> 5;

    size_t base = (size_t)bh * T_DIM * 64;

    bf16x8 qBh[4], qBl[4];
    {
        size_t qoff = base + (size_t)(qt * 128 + w * 32 + l31) * 64 + hs * 8;
#pragma unroll
        for (int st = 0; st < 4; ++st) {
            qBh[st] = *reinterpret_cast<const bf16x8*>(qh_g + qoff + st * 16);
            qBl[st] = *reinterpret_cast<const bf16x8*>(ql_g + qoff + st * 16);
        }
    }

    f32x16 oacc0 = zero16(), oacc1 = zero16();   // O^T frags: col=q(lane), regs=d
    float m = -1e30f, lsum = 0.f;

    int r8 = lane >> 3, c7 = lane & 7;
    int csrcK = c7 ^ r8;                 // KH source swizzle (row&7 == r8)
    int d4 = lane >> 4, s15 = lane & 15;

    auto stage = [&](int bs, int rt) {
        unsigned char* KH = smem + bs * 32768;
        unsigned char* VT = smem + bs * 32768 + 16384;
#pragma unroll
        for (int ci = 0; ci < 4; ++ci) {
            int chunk = w * 4 + ci;
            int row = chunk * 8 + r8;
            gload16(kh_g + base + (size_t)(rt * 128 + row) * 64 + csrcK * 8,
                    KH + chunk * 1024 + lane * 16);
        }
#pragma unroll
        for (int ci = 0; ci < 4; ++ci) {
            int chunk = w * 4 + ci;
            int d = chunk * 4 + d4;
            int cdat = (s15 & 8) | ((s15 ^ d) & 7);
            gload16(vT_g + base + (size_t)d * T_DIM + rt * 128 + cdat * 8,
                    VT + chunk * 1024 + lane * 16);
        }
    };

    stage(0, 0);
    __syncthreads();

    for (int rt = 0; rt <= qt; ++rt) {
        if (rt < qt) stage((rt + 1) & 1, rt + 1);   // prefetch next (not waited)
        const unsigned char* KH = smem + (rt & 1) * 32768;
        const unsigned char* VT = smem + (rt & 1) * 32768 + 16384;

        // ---- QK^T for one 32-krow subtile: S^T = K' x Q (hi + lo) ----
        auto qk = [&](int kt) -> f32x16 {
            int krow = kt * 32 + l31;
            f32x16 s = zero16();
            __builtin_amdgcn_s_setprio(1);
#pragma unroll
            for (int st = 0; st < 4; ++st) {
                int slot = (st * 2 + hs) ^ (krow & 7);
                bf16x8 kf = *reinterpret_cast<const bf16x8*>(KH + krow * 128 + slot * 16);
                s = MFMA32(kf, qBh[st], s);
                s = MFMA32(kf, qBl[st], s);
            }
            __builtin_amdgcn_s_setprio(0);
            return s;
        };

        // ---- softmax (defer-max) + P-conversion + PV for one subtile ----
        auto smpv = [&](f32x16& s, int kt, bool diag) {
            if (diag) {
#pragma unroll
                for (int r = 0; r < 16; ++r) {
                    int rowp = (r & 3) + 8 * (r >> 2) + 4 * hs;
                    if (rowp > l31) s[r] = -1e30f;   // mask krow > q
                }
            }
            float h0 = fmaxf(fmaxf(s[0], s[1]), s[2]);
            h0 = fmaxf(fmaxf(h0, s[3]), s[4]);
            h0 = fmaxf(fmaxf(h0, s[5]), s[6]);
            float h1 = fmaxf(fmaxf(s[8], s[9]), s[10]);
            h1 = fmaxf(fmaxf(h1, s[11]), s[12]);
            h1 = fmaxf(fmaxf(h1, s[13]), s[14]);
            float pmax = fmaxf(fmaxf(h0, s[7]), fmaxf(h1, s[15]));
            pmax = fmaxf(pmax, __shfl_xor(pmax, 32));
            if (__ballot(pmax > m + 8.f)) {      // defer-max: p <= 2^8, bf16-safe
                float mn = fmaxf(m, pmax);
                float sc = __builtin_amdgcn_exp2f(m - mn);
                m = mn; lsum *= sc;
#pragma unroll
                for (int r = 0; r < 16; ++r) { oacc0[r] *= sc; oacc1[r] *= sc; }
            }
            float p[16], psum = 0.f;
#pragma unroll
            for (int r = 0; r < 16; ++r) {
                p[r] = __builtin_amdgcn_exp2f(s[r] - m);
                psum += p[r];
            }
            lsum += psum + __shfl_xor(psum, 32);

            unsigned int wp[8];
#pragma unroll
            for (int q2 = 0; q2 < 2; ++q2) {
                int o = q2 * 8, d2 = q2 * 4;
                asm("v_cvt_pk_bf16_f32 %0, %1, %2" : "=v"(wp[d2+0]) : "v"(p[o+0]), "v"(p[o+1]));
                asm("v_cvt_pk_bf16_f32 %0, %1, %2" : "=v"(wp[d2+1]) : "v"(p[o+2]), "v"(p[o+3]));
                asm("v_cvt_pk_bf16_f32 %0, %1, %2" : "=v"(wp[d2+2]) : "v"(p[o+4]), "v"(p[o+5]));
                asm("v_cvt_pk_bf16_f32 %0, %1, %2" : "=v"(wp[d2+3]) : "v"(p[o+6]), "v"(p[o+7]));
                asm("v_permlane32_swap_b32 %0, %1" : "+v"(wp[d2+0]), "+v"(wp[d2+2]));
                asm("v_permlane32_swap_b32 %0, %1" : "+v"(wp[d2+1]), "+v"(wp[d2+3]));
            }
            union { unsigned int u[4]; bf16x8 v; } pa0, pa1;
            pa0.u[0] = wp[0]; pa0.u[1] = wp[1]; pa0.u[2] = wp[2]; pa0.u[3] = wp[3];
            pa1.u[0] = wp[4]; pa1.u[1] = wp[5]; pa1.u[2] = wp[6]; pa1.u[3] = wp[7];
            __builtin_amdgcn_s_setprio(1);
#pragma unroll
            for (int half = 0; half < 2; ++half) {
                const bf16x8 pv = half ? pa1.v : pa0.v;
#pragma unroll
                for (int dt = 0; dt < 2; ++dt) {
                    int d = dt * 32 + l31;
                    int c = kt * 4 + half * 2 + hs;
                    int slot = (c & 8) | ((c ^ d) & 7);
                    bf16x8 vb = *reinterpret_cast<const bf16x8*>(VT + d * 256 + slot * 16);
                    if (dt == 0) oacc0 = MFMA32(vb, pv, oacc0);
                    else         oacc1 = MFMA32(vb, pv, oacc1);
                }
            }
            __builtin_amdgcn_s_setprio(0);
        };

        // ---- 2-deep pipeline over the (up to 4) kt subtiles ----
        bool dg = (rt == qt);
        int kmax = dg ? w : 3;            // last kt index
        f32x16 s0 = qk(0);
        if (kmax == 0) {
            smpv(s0, 0, dg);
        } else {
            f32x16 s1 = qk(1);
            smpv(s0, 0, false);
            if (kmax == 1) {
                smpv(s1, 1, dg);
            } else {
                s0 = qk(2);
                smpv(s1, 1, false);
                if (kmax == 2) {
                    smpv(s0, 2, dg);
                } else {
                    s1 = qk(3);
                    smpv(s0, 2, false);
                    smpv(s1, 3, dg);
                }
            }
        }
        __syncthreads();   // drains prefetch + all LDS reads of this buffer done
    }

    // ---- epilogue: normalize (lane-local), stage OT[d][q], store attT bf16 ----
    float inv = 1.f / lsum;
#pragma unroll
    for (int r = 0; r < 16; ++r) {
        int rowp = (r & 3) + 8 * (r >> 2) + 4 * hs;   // d-row within 32
        OT[(rowp)      * 132 + w * 32 + l31] = oacc0[r] * inv;
        OT[(32 + rowp) * 132 + w * 32 + l31] = oacc1[r] * inv;
    }
    __syncthreads();
    {
        int d = tid >> 2, qb = tid & 3;
        unsigned short tmp[32];
#pragma unroll
        for (int i = 0; i < 8; ++i) {
            f32x4 v = *reinterpret_cast<const f32x4*>(&OT[d * 132 + qb * 32 + i * 4]);
            tmp[i*4+0] = f2bf(v[0]); tmp[i*4+1] = f2bf(v[1]);
            tmp[i*4+2] = f2bf(v[2]); tmp[i*4+3] = f2bf(v[3]);
        }
        unsigned short* dst = attT + ((size_t)bh * 64 + d) * T_DIM + qt * 128 + qb * 32;
        *reinterpret_cast<u16x8*>(dst)      = *reinterpret_cast<u16x8*>(&tmp[0]);
        *reinterpret_cast<u16x8*>(dst + 8)  = *reinterpret_cast<u16x8*>(&tmp[8]);
        *reinterpret_cast<u16x8*>(dst + 16) = *reinterpret_cast<u16x8*>(&tmp[16]);
        *reinterpret_cast<u16x8*>(dst + 24) = *reinterpret_cast<u16x8*>(&tmp[24]);
    }
}

// ---------------- Kernel 3: out = attT(as [4096][1024]) @ Wr^T + br ----------
__global__ __launch_bounds__(256) void final_gemm_mfma(
    const unsigned short* __restrict__ A, const unsigned short* __restrict__ Bw,
    const float* __restrict__ br, float* __restrict__ out)
{
    __shared__ __align__(16) unsigned short gsm[9216];
    int nt = blockIdx.x;
    int mt = blockIdx.y;
    int tid = threadIdx.x;
    int w = tid >> 6;
    int lane = tid & 63;
    int l15 = lane & 15;
    int l4 = lane >> 4;
    int ch = tid & 7;

    f32x4 acc[4];
#pragma unroll
    for (int n = 0; n < 4; ++n) acc[n] = (f32x4){0.f, 0.f, 0.f, 0.f};

    u16x8 rr[4];
#pragma unroll
    for (int k2 = 0; k2 < 4; ++k2) {
        int row = ((tid >> 3) + 32 * k2) & 63;
        const unsigned short* src = (k2 >= 2)
            ? Bw + (size_t)(nt * 64 + row) * 1024 + ch * 8
            : A  + (size_t)(mt * 64 + row) * 1024 + ch * 8;
        rr[k2] = *reinterpret_cast<const u16x8*>(src);
    }

#pragma unroll
    for (int kt = 0; kt < 16; ++kt) {
#pragma unroll
        for (int k2 = 0; k2 < 4; ++k2) {
            int row = ((tid >> 3) + 32 * k2) & 63;
            *reinterpret_cast<u16x8*>(&gsm[(k2 >> 1) * 4608 + row * 72 + ch * 8]) = rr[k2];
        }
        __syncthreads();
        u16x8 rnext[4];
        if (kt < 15) {
#pragma unroll
            for (int k2 = 0; k2 < 4; ++k2) {
                int row = ((tid >> 3) + 32 * k2) & 63;
                const unsigned short* src = (k2 >= 2)
                    ? Bw + (size_t)(nt * 64 + row) * 1024 + (kt + 1) * 64 + ch * 8
                    : A  + (size_t)(mt * 64 + row) * 1024 + (kt + 1) * 64 + ch * 8;
                rnext[k2] = *reinterpret_cast<const u16x8*>(src);
            }
        }
        bf16x8 a0 = *reinterpret_cast<const bf16x8*>(&gsm[(w * 16 + l15) * 72 + l4 * 8]);
        bf16x8 a1 = *reinterpret_cast<const bf16x8*>(&gsm[(w * 16 + l15) * 72 + 32 + l4 * 8]);
#pragma unroll
        for (int n = 0; n < 4; ++n) {
            bf16x8 b0 = *reinterpret_cast<const bf16x8*>(&gsm[4608 + (n * 16 + l15) * 72 + l4 * 8]);
            bf16x8 b1 = *reinterpret_cast<const bf16x8*>(&gsm[4608 + (n * 16 + l15) * 72 + 32 + l4 * 8]);
            acc[n] = MFMA16(a0, b0, acc[n]);
            acc[n] = MFMA16(a1, b1, acc[n]);
        }
        __syncthreads();
#pragma unroll
        for (int k2 = 0; k2 < 4; ++k2) rr[k2] = rnext[k2];
    }

#pragma unroll
    for (int n = 0; n < 4; ++n) {
        int col = nt * 64 + n * 16 + l15;
        float bias = br[col];
#pragma unroll
        for (int r = 0; r < 4; ++r) {
            int row = mt * 64 + w * 16 + l4 * 4 + r;
            out[(size_t)row * 1024 + col] = acc[n][r] + bias;
        }
    }
}

extern "C" void kernel_launch(void* const* d_in, const int* in_sizes, int n_in,
                              void* d_out, int out_size, void* d_ws, size_t ws_size,
                              hipStream_t stream) {
    const float* x  = (const float*)d_in[0];
    const float* Wq = (const float*)d_in[1];
    const float* Wk = (const float*)d_in[2];
    const float* Wv = (const float*)d_in[3];
    const float* Er = (const float*)d_in[4];
    const float* Wr = (const float*)d_in[5];
    const float* br = (const float*)d_in[6];
    float* out = (float*)d_out;

    const size_t nQ = (size_t)B_DIM * H_DIM * T_DIM * S_DIM;   // 4,194,304
    char* p = (char*)d_ws;
    unsigned short* qh = (unsigned short*)p;   p += nQ * 2;
    unsigned short* ql = (unsigned short*)p;   p += nQ * 2;
    unsigned short* kh = (unsigned short*)p;   p += nQ * 2;
    unsigned short* vT = (unsigned short*)p;   p += nQ * 2;
    unsigned short* attT = (unsigned short*)p; p += nQ * 2;
    unsigned short* wrb = (unsigned short*)p;  p += (size_t)E_DIM * E_DIM * 2;
    unsigned short* whi = (unsigned short*)p;  p += (size_t)3 * 65536 * 2;
    unsigned short* wlo = (unsigned short*)p;  p += (size_t)3 * 65536 * 2;
    size_t need = (size_t)(p - (char*)d_ws);
    if (ws_size < need) {
        fprintf(stderr, "WS TOO SMALL: have %zu need %zu\n", ws_size, need);
        return;
    }

    prep_w<<<1792, 256, 0, stream>>>(Wq, Wk, Wv, Wr, whi, wlo, wrb);
    qkv_mfma<<<4096, 64, 0, stream>>>(x, whi, wlo, Er, qh, ql, kh, vT);
    attn_mfma32<<<512, 256, 0, stream>>>(qh, ql, kh, vT, attT);
    final_gemm_mfma<<<dim3(16, 64), 256, 0, stream>>>(attT, wrb, br, out);
}

// Round 8
// 98.388 us; speedup vs baseline: 1.2617x; 1.0827x over previous
//
#include <hip/hip_runtime.h>
#include <hip/hip_bf16.h>
#include <cstdio>

#define T_DIM 2048
#define B_DIM 2
#define E_DIM 1024
#define H_DIM 16
#define S_DIM 64
#define LOG2E 1.44269504088896340736f

typedef __attribute__((ext_vector_type(4))) float f32x4;
typedef __attribute__((ext_vector_type(16))) float f32x16;
typedef __attribute__((ext_vector_type(8))) short bf16x8;
typedef __attribute__((ext_vector_type(8))) unsigned short u16x8;
typedef __attribute__((ext_vector_type(4))) unsigned short u16x4;

#define MFMA16(a,b,c) __builtin_amdgcn_mfma_f32_16x16x32_bf16((a),(b),(c),0,0,0)
#define MFMA32(a,b,c) __builtin_amdgcn_mfma_f32_32x32x16_bf16((a),(b),(c),0,0,0)

__device__ __forceinline__ unsigned short f2bf(float f) {
    union { __hip_bfloat16 h; unsigned short u; } c;
    c.h = __float2bfloat16(f);
    return c.u;
}
__device__ __forceinline__ float bf2f(unsigned short u) {
    union { __hip_bfloat16 h; unsigned short u; } c;
    c.u = u;
    return __bfloat162float(c.h);
}
__device__ __forceinline__ void gload16(const void* g, void* l) {
    __builtin_amdgcn_global_load_lds(
        (const __attribute__((address_space(1))) unsigned int*)g,
        (__attribute__((address_space(3))) unsigned int*)l, 16, 0, 0);
}
__device__ __forceinline__ f32x16 zero16() {
    f32x16 v;
#pragma unroll
    for (int i = 0; i < 16; ++i) v[i] = 0.f;
    return v;
}

// ---------------- Kernel 0: weight prep (split Wq/Wk/Wv hi/lo + Wr->bf16) ----
__global__ __launch_bounds__(256) void prep_w(
    const float* __restrict__ Wq, const float* __restrict__ Wk,
    const float* __restrict__ Wv, const float* __restrict__ Wr,
    unsigned short* __restrict__ whi, unsigned short* __restrict__ wlo,
    unsigned short* __restrict__ wrb)
{
    int bid = blockIdx.x;
    if (bid < 768) {
        int i = bid * 256 + threadIdx.x;   // < 196608
        const float* src = (i < 65536) ? Wq : ((i < 131072) ? Wk : Wv);
        float v = src[i & 65535];
        unsigned short h = f2bf(v);
        whi[i] = h;
        wlo[i] = f2bf(v - bf2f(h));
    } else {
        int i = (bid - 768) * 256 + threadIdx.x;   // < 262144
        float4 v = reinterpret_cast<const float4*>(Wr)[i];
        u16x4 o;
        o[0] = f2bf(v.x); o[1] = f2bf(v.y); o[2] = f2bf(v.z); o[3] = f2bf(v.w);
        *reinterpret_cast<u16x4*>(wrb + (size_t)i * 4) = o;
    }
}

// ---------------- Kernel 1: QKV projection via hi/lo bf16 MFMA ----------------
__global__ __launch_bounds__(64) void qkv_mfma(
    const float* __restrict__ x, const unsigned short* __restrict__ whi,
    const unsigned short* __restrict__ wlo, const float* __restrict__ Er,
    unsigned short* __restrict__ qh_g, unsigned short* __restrict__ ql_g,
    unsigned short* __restrict__ kh_g, unsigned short* __restrict__ vT_g)
{
    int bid = blockIdx.x;
    int dg = bid & 1;
    int tt = (bid >> 1) & 63;
    int h  = (bid >> 7) & 15;
    int b  = bid >> 11;
    int bh = b * H_DIM + h;
    int t0 = tt * 32;
    int lane = threadIdx.x;
    int l31 = lane & 31, hs = lane >> 5;

    bf16x8 xh[4], xl[4];
    const float* xrow = x + (size_t)(t0 + l31) * (B_DIM * E_DIM) + (size_t)b * E_DIM + h * 64;
#pragma unroll
    for (int ks = 0; ks < 4; ++ks) {
        float vv[8];
        *reinterpret_cast<float4*>(&vv[0]) = *reinterpret_cast<const float4*>(xrow + ks * 16 + hs * 8);
        *reinterpret_cast<float4*>(&vv[4]) = *reinterpret_cast<const float4*>(xrow + ks * 16 + hs * 8 + 4);
        unsigned short hh[8], ll[8];
#pragma unroll
        for (int j = 0; j < 8; ++j) {
            hh[j] = f2bf(vv[j]);
            ll[j] = f2bf(vv[j] - bf2f(hh[j]));
        }
        xh[ks] = *reinterpret_cast<bf16x8*>(hh);
        xl[ks] = *reinterpret_cast<bf16x8*>(ll);
    }

    f32x16 aq = zero16(), ak = zero16(), av = zero16();
    size_t wofs = (size_t)h * 4096 + (size_t)(dg * 32 + l31) * 64 + hs * 8;
    const unsigned short* whp = whi + wofs;
    const unsigned short* wlp = wlo + wofs;
#pragma unroll
    for (int ks = 0; ks < 4; ++ks) {
        bf16x8 qwh = *reinterpret_cast<const bf16x8*>(whp + ks * 16);
        bf16x8 qwl = *reinterpret_cast<const bf16x8*>(wlp + ks * 16);
        bf16x8 kwh = *reinterpret_cast<const bf16x8*>(whp + 65536 + ks * 16);
        bf16x8 kwl = *reinterpret_cast<const bf16x8*>(wlp + 65536 + ks * 16);
        bf16x8 vwh = *reinterpret_cast<const bf16x8*>(whp + 131072 + ks * 16);
        bf16x8 vwl = *reinterpret_cast<const bf16x8*>(wlp + 131072 + ks * 16);
        aq = MFMA32(xh[ks], qwh, aq);
        aq = MFMA32(xl[ks], qwh, aq);
        aq = MFMA32(xh[ks], qwl, aq);
        ak = MFMA32(xh[ks], kwh, ak);
        ak = MFMA32(xl[ks], kwh, ak);
        ak = MFMA32(xh[ks], kwl, ak);
        av = MFMA32(vwh, xh[ks], av);   // v computed transposed: D = W*x^T
        av = MFMA32(vwh, xl[ks], av);
        av = MFMA32(vwl, xh[ks], av);
    }

    size_t rowbase = (size_t)bh * T_DIM * 64;
#pragma unroll
    for (int r = 0; r < 16; ++r) {
        int rowp = (r & 3) + 8 * (r >> 2) + 4 * hs;
        int t = t0 + rowp;
        int d = dg * 32 + l31;
        size_t ro = rowbase + (size_t)t * 64 + d;
        float qv = aq[r];
        unsigned short qhi = f2bf(qv);
        qh_g[ro] = qhi;
        ql_g[ro] = f2bf(qv - bf2f(qhi));
        float kv = (ak[r] * 0.03125f + Er[(size_t)d * T_DIM + t]) * LOG2E;
        kh_g[ro] = f2bf(kv);
        vT_g[((size_t)bh * 64 + dg * 32 + rowp) * T_DIM + t0 + l31] = f2bf(av[r]);
    }
}

// ---------------- Kernel 2: causal flash attention, in-block K-split ---------
// Block: 8 waves (512 thr) over 128 q-rows. Waves 0-3 = K-half 0 (even 64-row
// K-tiles), waves 4-7 = K-half 1 (odd tiles) -> 4096 waves device-wide
// (4/SIMD) instead of 2048. Each half: dbuf-staged K[64][64] + V^T[64][64]
// (xor-swizzled), 2 subtiles of 32 k-rows per tile, swapped QK^T (lane-local
// softmax, defer-max), PV as O^T = V^T x P^T, P in-register via cvt_pk +
// permlane32_swap. Halves merge (m,l,O) in-LDS at the end (layouts match
// register-for-register). LDS 64KB -> 2 blocks/CU = 16 waves/CU.
__global__ __launch_bounds__(512, 4) void attn_mfma32(
    const unsigned short* __restrict__ qh_g, const unsigned short* __restrict__ ql_g,
    const unsigned short* __restrict__ kh_g, const unsigned short* __restrict__ vT_g,
    unsigned short* __restrict__ attT)
{
    __shared__ __align__(16) unsigned char smem[65536];
    float* OT  = (float*)smem;            // [64][132] f32 (epilogue)
    float* MRG = (float*)smem;            // [4][32][64] f32 = 32KB (merge)
    float* ML  = (float*)(smem + 32768);  // [128][2] f32 (merge m,l)

    int bid = blockIdx.x;
    int bh = bid & 31;            // all 16 blocks of a head -> same XCD (L2 reuse)
    int u = bid >> 5;
    int qt = (u < 8) ? (15 - u) : (u - 8);  // heavy first; co-CU pairs sum 15

    int tid = threadIdx.x;
    int w = tid >> 6;         // 0..7
    int half = w >> 2;        // K-split half
    int wq = w & 3;           // q sub-block
    int lane = tid & 63;
    int l31 = lane & 31;
    int hs = lane >> 5;
    int q_lo = qt * 128 + wq * 32;

    size_t base = (size_t)bh * T_DIM * 64;

    // Q fragments (held in registers)
    bf16x8 qBh[4], qBl[4];
    {
        size_t qoff = base + (size_t)(q_lo + l31) * 64 + hs * 8;
#pragma unroll
        for (int st = 0; st < 4; ++st) {
            qBh[st] = *reinterpret_cast<const bf16x8*>(qh_g + qoff + st * 16);
            qBl[st] = *reinterpret_cast<const bf16x8*>(ql_g + qoff + st * 16);
        }
    }

    f32x16 oacc0 = zero16(), oacc1 = zero16();   // O^T frags: col=q(lane), regs=d
    float m = -1e30f, lsum = 0.f;

    int srow = lane >> 3;     // staging row-in-group
    int scol = lane & 7;      // staging slot (pre-swizzle)

    // stage one 64-row K-tile + V-tile into this half's dbuf slot
    auto stage = [&](int bs, int k0) {
        unsigned char* KH = smem + half * 32768 + bs * 16384;
        unsigned char* VT = KH + 8192;
#pragma unroll
        for (int i = 0; i < 2; ++i) {
            int row = i * 32 + wq * 8 + srow;
            gload16(kh_g + base + (size_t)(k0 + row) * 64 + (scol ^ (row & 7)) * 8,
                    KH + i * 4096 + wq * 1024 + lane * 16);
        }
#pragma unroll
        for (int i = 0; i < 2; ++i) {
            int d = i * 32 + wq * 8 + srow;
            gload16(vT_g + base + (size_t)d * T_DIM + k0 + ((scol ^ (d & 7)) * 8),
                    VT + i * 4096 + wq * 1024 + lane * 16);
        }
    };

    // QK^T subtile: S^T = K' x Q (hi + lo), col=q=l31, regs=krow
    auto qk = [&](const unsigned char* KH, int kt) -> f32x16 {
        int krow = kt * 32 + l31;
        f32x16 s = zero16();
        __builtin_amdgcn_s_setprio(1);
#pragma unroll
        for (int st = 0; st < 4; ++st) {
            int slot = (st * 2 + hs) ^ (krow & 7);
            bf16x8 kf = *reinterpret_cast<const bf16x8*>(KH + krow * 128 + slot * 16);
            s = MFMA32(kf, qBh[st], s);
            s = MFMA32(kf, qBl[st], s);
        }
        __builtin_amdgcn_s_setprio(0);
        return s;
    };

    // softmax (defer-max) + P conversion + PV for one subtile
    auto smpv = [&](f32x16& s, const unsigned char* VT, int kt, bool diag) {
        if (diag) {
#pragma unroll
            for (int r = 0; r < 16; ++r) {
                int rowp = (r & 3) + 8 * (r >> 2) + 4 * hs;
                if (rowp > l31) s[r] = -1e30f;   // mask krow > q
            }
        }
        float h0 = fmaxf(fmaxf(s[0], s[1]), s[2]);
        h0 = fmaxf(fmaxf(h0, s[3]), s[4]);
        h0 = fmaxf(fmaxf(h0, s[5]), s[6]);
        float h1 = fmaxf(fmaxf(s[8], s[9]), s[10]);
        h1 = fmaxf(fmaxf(h1, s[11]), s[12]);
        h1 = fmaxf(fmaxf(h1, s[13]), s[14]);
        float pmax = fmaxf(fmaxf(h0, s[7]), fmaxf(h1, s[15]));
        pmax = fmaxf(pmax, __shfl_xor(pmax, 32));
        if (__ballot(pmax > m + 8.f)) {      // defer-max: p <= 2^8, bf16-safe
            float mn = fmaxf(m, pmax);
            float sc = __builtin_amdgcn_exp2f(m - mn);
            m = mn; lsum *= sc;
#pragma unroll
            for (int r = 0; r < 16; ++r) { oacc0[r] *= sc; oacc1[r] *= sc; }
        }
        float p[16], psum = 0.f;
#pragma unroll
        for (int r = 0; r < 16; ++r) {
            p[r] = __builtin_amdgcn_exp2f(s[r] - m);
            psum += p[r];
        }
        lsum += psum + __shfl_xor(psum, 32);

        unsigned int wp[8];
#pragma unroll
        for (int q2 = 0; q2 < 2; ++q2) {
            int o = q2 * 8, d2 = q2 * 4;
            asm("v_cvt_pk_bf16_f32 %0, %1, %2" : "=v"(wp[d2+0]) : "v"(p[o+0]), "v"(p[o+1]));
            asm("v_cvt_pk_bf16_f32 %0, %1, %2" : "=v"(wp[d2+1]) : "v"(p[o+2]), "v"(p[o+3]));
            asm("v_cvt_pk_bf16_f32 %0, %1, %2" : "=v"(wp[d2+2]) : "v"(p[o+4]), "v"(p[o+5]));
            asm("v_cvt_pk_bf16_f32 %0, %1, %2" : "=v"(wp[d2+3]) : "v"(p[o+6]), "v"(p[o+7]));
            asm("v_permlane32_swap_b32 %0, %1" : "+v"(wp[d2+0]), "+v"(wp[d2+2]));
            asm("v_permlane32_swap_b32 %0, %1" : "+v"(wp[d2+1]), "+v"(wp[d2+3]));
        }
        union { unsigned int u[4]; bf16x8 v; } pa0, pa1;
        pa0.u[0] = wp[0]; pa0.u[1] = wp[1]; pa0.u[2] = wp[2]; pa0.u[3] = wp[3];
        pa1.u[0] = wp[4]; pa1.u[1] = wp[5]; pa1.u[2] = wp[6]; pa1.u[3] = wp[7];
        __builtin_amdgcn_s_setprio(1);
#pragma unroll
        for (int ph = 0; ph < 2; ++ph) {
            const bf16x8 pv = ph ? pa1.v : pa0.v;
#pragma unroll
            for (int dt = 0; dt < 2; ++dt) {
                int d = dt * 32 + l31;
                int c = kt * 4 + ph * 2 + hs;
                int slot = c ^ (d & 7);
                bf16x8 vb = *reinterpret_cast<const bf16x8*>(VT + d * 128 + slot * 16);
                if (dt == 0) oacc0 = MFMA32(vb, pv, oacc0);
                else         oacc1 = MFMA32(vb, pv, oacc1);
            }
        }
        __builtin_amdgcn_s_setprio(0);
    };

    // ---- main loop: qt+1 tiles per half, lockstep barriers ----
    stage(0, half * 64);
    __syncthreads();
    for (int i = 0; i <= qt; ++i) {
        int k0 = (half + 2 * i) * 64;
        if (i < qt) stage((i + 1) & 1, (half + 2 * (i + 1)) * 64);
        const unsigned char* KH = smem + half * 32768 + (i & 1) * 16384;
        const unsigned char* VT = KH + 8192;

        bool skip0 = k0 > q_lo;          // subtile fully above diagonal
        bool skip1 = k0 + 32 > q_lo;
        bool diag0 = k0 == q_lo;
        bool diag1 = k0 + 32 == q_lo;
        if (!skip1) {                    // both subtiles live (2-deep pipeline)
            f32x16 s0 = qk(KH, 0);
            f32x16 s1 = qk(KH, 1);
            smpv(s0, VT, 0, diag0);
            smpv(s1, VT, 1, diag1);
        } else if (!skip0) {             // only subtile 0 (diag or last)
            f32x16 s0 = qk(KH, 0);
            smpv(s0, VT, 0, diag0);
        }
        __syncthreads();   // drains prefetch; guards dbuf reuse
    }

    // ---- merge the two K-halves in-LDS (layouts match reg-for-reg) ----
    if (half == 1) {
#pragma unroll
        for (int r = 0; r < 16; ++r) {
            MRG[(wq * 32 + r) * 64 + lane]      = oacc0[r];
            MRG[(wq * 32 + 16 + r) * 64 + lane] = oacc1[r];
        }
        if (hs == 0) {
            ML[(wq * 32 + l31) * 2]     = m;
            ML[(wq * 32 + l31) * 2 + 1] = lsum;
        }
    }
    __syncthreads();
    float inv = 0.f;
    if (half == 0) {
        float m1 = ML[(wq * 32 + l31) * 2];
        float l1 = ML[(wq * 32 + l31) * 2 + 1];
        float mm = fmaxf(m, m1);
        float w0 = __builtin_amdgcn_exp2f(m - mm);
        float w1 = __builtin_amdgcn_exp2f(m1 - mm);
        lsum = lsum * w0 + l1 * w1;
        inv = 1.f / lsum;
#pragma unroll
        for (int r = 0; r < 16; ++r) {
            oacc0[r] = oacc0[r] * w0 + MRG[(wq * 32 + r) * 64 + lane] * w1;
            oacc1[r] = oacc1[r] * w0 + MRG[(wq * 32 + 16 + r) * 64 + lane] * w1;
        }
    }
    __syncthreads();   // merge reads done before OT overwrite

    // ---- epilogue: normalize, stage OT[d][q], store attT bf16 ----
    if (half == 0) {
#pragma unroll
        for (int r = 0; r < 16; ++r) {
            int rowp = (r & 3) + 8 * (r >> 2) + 4 * hs;   // d-row within 32
            OT[(rowp)      * 132 + wq * 32 + l31] = oacc0[r] * inv;
            OT[(32 + rowp) * 132 + wq * 32 + l31] = oacc1[r] * inv;
        }
    }
    __syncthreads();
    {
        int d = tid >> 3, qb = tid & 7;   // 64 d x 8 groups of 16 q
        unsigned short tmp[16];
#pragma unroll
        for (int i = 0; i < 4; ++i) {
            f32x4 v = *reinterpret_cast<const f32x4*>(&OT[d * 132 + qb * 16 + i * 4]);
            tmp[i*4+0] = f2bf(v[0]); tmp[i*4+1] = f2bf(v[1]);
            tmp[i*4+2] = f2bf(v[2]); tmp[i*4+3] = f2bf(v[3]);
        }
        unsigned short* dst = attT + ((size_t)bh * 64 + d) * T_DIM + qt * 128 + qb * 16;
        *reinterpret_cast<u16x8*>(dst)     = *reinterpret_cast<u16x8*>(&tmp[0]);
        *reinterpret_cast<u16x8*>(dst + 8) = *reinterpret_cast<u16x8*>(&tmp[8]);
    }
}

// ---------------- Kernel 3: out = attT(as [4096][1024]) @ Wr^T + br ----------
__global__ __launch_bounds__(256) void final_gemm_mfma(
    const unsigned short* __restrict__ A, const unsigned short* __restrict__ Bw,
    const float* __restrict__ br, float* __restrict__ out)
{
    __shared__ __align__(16) unsigned short gsm[9216];
    int nt = blockIdx.x;
    int mt = blockIdx.y;
    int tid = threadIdx.x;
    int w = tid >> 6;
    int lane = tid & 63;
    int l15 = lane & 15;
    int l4 = lane >> 4;
    int ch = tid & 7;

    f32x4 acc[4];
#pragma unroll
    for (int n = 0; n < 4; ++n) acc[n] = (f32x4){0.f, 0.f, 0.f, 0.f};

    u16x8 rr[4];
#pragma unroll
    for (int k2 = 0; k2 < 4; ++k2) {
        int row = ((tid >> 3) + 32 * k2) & 63;
        const unsigned short* src = (k2 >= 2)
            ? Bw + (size_t)(nt * 64 + row) * 1024 + ch * 8
            : A  + (size_t)(mt * 64 + row) * 1024 + ch * 8;
        rr[k2] = *reinterpret_cast<const u16x8*>(src);
    }

#pragma unroll
    for (int kt = 0; kt < 16; ++kt) {
#pragma unroll
        for (int k2 = 0; k2 < 4; ++k2) {
            int row = ((tid >> 3) + 32 * k2) & 63;
            *reinterpret_cast<u16x8*>(&gsm[(k2 >> 1) * 4608 + row * 72 + ch * 8]) = rr[k2];
        }
        __syncthreads();
        u16x8 rnext[4];
        if (kt < 15) {
#pragma unroll
            for (int k2 = 0; k2 < 4; ++k2) {
                int row = ((tid >> 3) + 32 * k2) & 63;
                const unsigned short* src = (k2 >= 2)
                    ? Bw + (size_t)(nt * 64 + row) * 1024 + (kt + 1) * 64 + ch * 8
                    : A  + (size_t)(mt * 64 + row) * 1024 + (kt + 1) * 64 + ch * 8;
                rnext[k2] = *reinterpret_cast<const u16x8*>(src);
            }
        }
        bf16x8 a0 = *reinterpret_cast<const bf16x8*>(&gsm[(w * 16 + l15) * 72 + l4 * 8]);
        bf16x8 a1 = *reinterpret_cast<const bf16x8*>(&gsm[(w * 16 + l15) * 72 + 32 + l4 * 8]);
#pragma unroll
        for (int n = 0; n < 4; ++n) {
            bf16x8 b0 = *reinterpret_cast<const bf16x8*>(&gsm[4608 + (n * 16 + l15) * 72 + l4 * 8]);
            bf16x8 b1 = *reinterpret_cast<const bf16x8*>(&gsm[4608 + (n * 16 + l15) * 72 + 32 + l4 * 8]);
            acc[n] = MFMA16(a0, b0, acc[n]);
            acc[n] = MFMA16(a1, b1, acc[n]);
        }
        __syncthreads();
#pragma unroll
        for (int k2 = 0; k2 < 4; ++k2) rr[k2] = rnext[k2];
    }

#pragma unroll
    for (int n = 0; n < 4; ++n) {
        int col = nt * 64 + n * 16 + l15;
        float bias = br[col];
#pragma unroll
        for (int r = 0; r < 4; ++r) {
            int row = mt * 64 + w * 16 + l4 * 4 + r;
            out[(size_t)row * 1024 + col] = acc[n][r] + bias;
        }
    }
}

extern "C" void kernel_launch(void* const* d_in, const int* in_sizes, int n_in,
                              void* d_out, int out_size, void* d_ws, size_t ws_size,
                              hipStream_t stream) {
    const float* x  = (const float*)d_in[0];
    const float* Wq = (const float*)d_in[1];
    const float* Wk = (const float*)d_in[2];
    const float* Wv = (const float*)d_in[3];
    const float* Er = (const float*)d_in[4];
    const float* Wr = (const float*)d_in[5];
    const float* br = (const float*)d_in[6];
    float* out = (float*)d_out;

    const size_t nQ = (size_t)B_DIM * H_DIM * T_DIM * S_DIM;   // 4,194,304
    char* p = (char*)d_ws;
    unsigned short* qh = (unsigned short*)p;   p += nQ * 2;
    unsigned short* ql = (unsigned short*)p;   p += nQ * 2;
    unsigned short* kh = (unsigned short*)p;   p += nQ * 2;
    unsigned short* vT = (unsigned short*)p;   p += nQ * 2;
    unsigned short* attT = (unsigned short*)p; p += nQ * 2;
    unsigned short* wrb = (unsigned short*)p;  p += (size_t)E_DIM * E_DIM * 2;
    unsigned short* whi = (unsigned short*)p;  p += (size_t)3 * 65536 * 2;
    unsigned short* wlo = (unsigned short*)p;  p += (size_t)3 * 65536 * 2;
    size_t need = (size_t)(p - (char*)d_ws);
    if (ws_size < need) {
        fprintf(stderr, "WS TOO SMALL: have %zu need %zu\n", ws_size, need);
        return;
    }

    prep_w<<<1792, 256, 0, stream>>>(Wq, Wk, Wv, Wr, whi, wlo, wrb);
    qkv_mfma<<<4096, 64, 0, stream>>>(x, whi, wlo, Er, qh, ql, kh, vT);
    attn_mfma32<<<512, 512, 0, stream>>>(qh, ql, kh, vT, attT);
    final_gemm_mfma<<<dim3(16, 64), 256, 0, stream>>>(attT, wrb, br, out);
}

// Round 9
// 78.300 us; speedup vs baseline: 1.5854x; 1.2566x over previous
//
#include <hip/hip_runtime.h>
#include <hip/hip_bf16.h>
#include <cstdio>

#define T_DIM 2048
#define B_DIM 2
#define E_DIM 1024
#define H_DIM 16
#define S_DIM 64
#define LOG2E 1.44269504088896340736f

typedef __attribute__((ext_vector_type(4))) float f32x4;
typedef __attribute__((ext_vector_type(16))) float f32x16;
typedef __attribute__((ext_vector_type(8))) short bf16x8;
typedef __attribute__((ext_vector_type(8))) unsigned short u16x8;
typedef __attribute__((ext_vector_type(4))) unsigned short u16x4;

#define MFMA32(a,b,c) __builtin_amdgcn_mfma_f32_32x32x16_bf16((a),(b),(c),0,0,0)

__device__ __forceinline__ unsigned short f2bf(float f) {
    union { __hip_bfloat16 h; unsigned short u; } c;
    c.h = __float2bfloat16(f);
    return c.u;
}
__device__ __forceinline__ float bf2f(unsigned short u) {
    union { __hip_bfloat16 h; unsigned short u; } c;
    c.u = u;
    return __bfloat162float(c.h);
}
__device__ __forceinline__ void gload16(const void* g, void* l) {
    __builtin_amdgcn_global_load_lds(
        (const __attribute__((address_space(1))) unsigned int*)g,
        (__attribute__((address_space(3))) unsigned int*)l, 16, 0, 0);
}
__device__ __forceinline__ f32x16 zero16() {
    f32x16 v;
#pragma unroll
    for (int i = 0; i < 16; ++i) v[i] = 0.f;
    return v;
}

// ---------------- Kernel 0: weight prep (all weights -> bf16) ----------------
// blocks [0,192): Wq|Wk|Wv -> whb (196608 elems, float4-vectorized).
// blocks [192,1216): Wr -> wrb (1M elems).
__global__ __launch_bounds__(256) void prep_w(
    const float* __restrict__ Wq, const float* __restrict__ Wk,
    const float* __restrict__ Wv, const float* __restrict__ Wr,
    unsigned short* __restrict__ whb, unsigned short* __restrict__ wrb)
{
    int bid = blockIdx.x;
    if (bid < 192) {
        int i = bid * 256 + threadIdx.x;   // float4 idx < 49152
        const float* src = (i < 16384) ? Wq : ((i < 32768) ? Wk : Wv);
        float4 v = reinterpret_cast<const float4*>(src)[i & 16383];
        u16x4 o;
        o[0] = f2bf(v.x); o[1] = f2bf(v.y); o[2] = f2bf(v.z); o[3] = f2bf(v.w);
        *reinterpret_cast<u16x4*>(whb + (size_t)i * 4) = o;
    } else {
        int i = (bid - 192) * 256 + threadIdx.x;   // float4 idx < 262144
        float4 v = reinterpret_cast<const float4*>(Wr)[i];
        u16x4 o;
        o[0] = f2bf(v.x); o[1] = f2bf(v.y); o[2] = f2bf(v.z); o[3] = f2bf(v.w);
        *reinterpret_cast<u16x4*>(wrb + (size_t)i * 4) = o;
    }
}

// ---------------- Kernel 1: QKV projection, plain bf16 MFMA ----------------
// One wave per block; 32 t x 32 d x {q,k,v}. MFMA accumulates fp32, so the
// only error is bf16 input quantization (~0.2% on scores, within threshold).
__global__ __launch_bounds__(64) void qkv_mfma(
    const float* __restrict__ x, const unsigned short* __restrict__ wb,
    const float* __restrict__ Er,
    unsigned short* __restrict__ qb_g, unsigned short* __restrict__ kh_g,
    unsigned short* __restrict__ vT_g)
{
    int bid = blockIdx.x;
    int dg = bid & 1;
    int tt = (bid >> 1) & 63;
    int h  = (bid >> 7) & 15;
    int b  = bid >> 11;
    int bh = b * H_DIM + h;
    int t0 = tt * 32;
    int lane = threadIdx.x;
    int l31 = lane & 31, hs = lane >> 5;

    bf16x8 xb[4];
    const float* xrow = x + (size_t)(t0 + l31) * (B_DIM * E_DIM) + (size_t)b * E_DIM + h * 64;
#pragma unroll
    for (int ks = 0; ks < 4; ++ks) {
        float vv[8];
        *reinterpret_cast<float4*>(&vv[0]) = *reinterpret_cast<const float4*>(xrow + ks * 16 + hs * 8);
        *reinterpret_cast<float4*>(&vv[4]) = *reinterpret_cast<const float4*>(xrow + ks * 16 + hs * 8 + 4);
        unsigned short hh[8];
#pragma unroll
        for (int j = 0; j < 8; ++j) hh[j] = f2bf(vv[j]);
        xb[ks] = *reinterpret_cast<bf16x8*>(hh);
    }

    f32x16 aq = zero16(), ak = zero16(), av = zero16();
    size_t wofs = (size_t)h * 4096 + (size_t)(dg * 32 + l31) * 64 + hs * 8;
#pragma unroll
    for (int ks = 0; ks < 4; ++ks) {
        bf16x8 qw = *reinterpret_cast<const bf16x8*>(wb + wofs + ks * 16);
        bf16x8 kw = *reinterpret_cast<const bf16x8*>(wb + 65536 + wofs + ks * 16);
        bf16x8 vw = *reinterpret_cast<const bf16x8*>(wb + 131072 + wofs + ks * 16);
        aq = MFMA32(xb[ks], qw, aq);
        ak = MFMA32(xb[ks], kw, ak);
        av = MFMA32(vw, xb[ks], av);   // v computed transposed: D = W*x^T
    }

    // epilogue: q bf16, k' = log2e*(k/32 + Er^T) bf16, vT bf16
    size_t rowbase = (size_t)bh * T_DIM * 64;
#pragma unroll
    for (int r = 0; r < 16; ++r) {
        int rowp = (r & 3) + 8 * (r >> 2) + 4 * hs;
        int t = t0 + rowp;
        int d = dg * 32 + l31;
        size_t ro = rowbase + (size_t)t * 64 + d;
        qb_g[ro] = f2bf(aq[r]);
        float kv = (ak[r] * 0.03125f + Er[(size_t)d * T_DIM + t]) * LOG2E;
        kh_g[ro] = f2bf(kv);
        vT_g[((size_t)bh * 64 + dg * 32 + rowp) * T_DIM + t0 + l31] = f2bf(av[r]);
    }
}

// ---------------- Kernel 2: causal flash attention, in-block K-split ---------
// Block: 8 waves (512 thr) over 128 q-rows; waves 0-3 even 64-row K-tiles,
// waves 4-7 odd -> 4096 waves device-wide. Plain-bf16 QK (4 MFMAs/subtile),
// lane-local softmax (defer-max), PV as O^T = V^T x P^T, P in-register via
// cvt_pk + permlane32_swap. Halves merge (m,l,O) in-LDS at the end.
__global__ __launch_bounds__(512, 4) void attn_mfma32(
    const unsigned short* __restrict__ qb_g, const unsigned short* __restrict__ kh_g,
    const unsigned short* __restrict__ vT_g, unsigned short* __restrict__ attT)
{
    __shared__ __align__(16) unsigned char smem[65536];
    float* OT  = (float*)smem;            // [64][132] f32 (epilogue)
    float* MRG = (float*)smem;            // [4][32][64] f32 = 32KB (merge)
    float* ML  = (float*)(smem + 32768);  // [128][2] f32 (merge m,l)

    int bid = blockIdx.x;
    int bh = bid & 31;            // all 16 blocks of a head -> same XCD (L2 reuse)
    int u = bid >> 5;
    int qt = (u < 8) ? (15 - u) : (u - 8);  // heavy first; co-CU pairs sum 15

    int tid = threadIdx.x;
    int w = tid >> 6;         // 0..7
    int half = w >> 2;        // K-split half
    int wq = w & 3;           // q sub-block
    int lane = tid & 63;
    int l31 = lane & 31;
    int hs = lane >> 5;
    int q_lo = qt * 128 + wq * 32;

    size_t base = (size_t)bh * T_DIM * 64;

    // Q fragments (held in registers)
    bf16x8 qB[4];
    {
        size_t qoff = base + (size_t)(q_lo + l31) * 64 + hs * 8;
#pragma unroll
        for (int st = 0; st < 4; ++st)
            qB[st] = *reinterpret_cast<const bf16x8*>(qb_g + qoff + st * 16);
    }

    f32x16 oacc0 = zero16(), oacc1 = zero16();   // O^T frags: col=q(lane), regs=d
    float m = -1e30f, lsum = 0.f;

    int srow = lane >> 3;     // staging row-in-group
    int scol = lane & 7;      // staging slot (pre-swizzle)

    // stage one 64-row K-tile + V-tile into this half's dbuf slot
    auto stage = [&](int bs, int k0) {
        unsigned char* KH = smem + half * 32768 + bs * 16384;
        unsigned char* VT = KH + 8192;
#pragma unroll
        for (int i = 0; i < 2; ++i) {
            int row = i * 32 + wq * 8 + srow;
            gload16(kh_g + base + (size_t)(k0 + row) * 64 + (scol ^ (row & 7)) * 8,
                    KH + i * 4096 + wq * 1024 + lane * 16);
        }
#pragma unroll
        for (int i = 0; i < 2; ++i) {
            int d = i * 32 + wq * 8 + srow;
            gload16(vT_g + base + (size_t)d * T_DIM + k0 + ((scol ^ (d & 7)) * 8),
                    VT + i * 4096 + wq * 1024 + lane * 16);
        }
    };

    // QK^T subtile: S^T = K' x Q, col=q=l31, regs=krow
    auto qk = [&](const unsigned char* KH, int kt) -> f32x16 {
        int krow = kt * 32 + l31;
        f32x16 s = zero16();
        __builtin_amdgcn_s_setprio(1);
#pragma unroll
        for (int st = 0; st < 4; ++st) {
            int slot = (st * 2 + hs) ^ (krow & 7);
            bf16x8 kf = *reinterpret_cast<const bf16x8*>(KH + krow * 128 + slot * 16);
            s = MFMA32(kf, qB[st], s);
        }
        __builtin_amdgcn_s_setprio(0);
        return s;
    };

    // softmax (defer-max) + P conversion + PV for one subtile
    auto smpv = [&](f32x16& s, const unsigned char* VT, int kt, bool diag) {
        if (diag) {
#pragma unroll
            for (int r = 0; r < 16; ++r) {
                int rowp = (r & 3) + 8 * (r >> 2) + 4 * hs;
                if (rowp > l31) s[r] = -1e30f;   // mask krow > q
            }
        }
        float h0 = fmaxf(fmaxf(s[0], s[1]), s[2]);
        h0 = fmaxf(fmaxf(h0, s[3]), s[4]);
        h0 = fmaxf(fmaxf(h0, s[5]), s[6]);
        float h1 = fmaxf(fmaxf(s[8], s[9]), s[10]);
        h1 = fmaxf(fmaxf(h1, s[11]), s[12]);
        h1 = fmaxf(fmaxf(h1, s[13]), s[14]);
        float pmax = fmaxf(fmaxf(h0, s[7]), fmaxf(h1, s[15]));
        pmax = fmaxf(pmax, __shfl_xor(pmax, 32));
        if (__ballot(pmax > m + 8.f)) {      // defer-max: p <= 2^8, bf16-safe
            float mn = fmaxf(m, pmax);
            float sc = __builtin_amdgcn_exp2f(m - mn);
            m = mn; lsum *= sc;
#pragma unroll
            for (int r = 0; r < 16; ++r) { oacc0[r] *= sc; oacc1[r] *= sc; }
        }
        float p[16], psum = 0.f;
#pragma unroll
        for (int r = 0; r < 16; ++r) {
            p[r] = __builtin_amdgcn_exp2f(s[r] - m);
            psum += p[r];
        }
        lsum += psum + __shfl_xor(psum, 32);

        unsigned int wp[8];
#pragma unroll
        for (int q2 = 0; q2 < 2; ++q2) {
            int o = q2 * 8, d2 = q2 * 4;
            asm("v_cvt_pk_bf16_f32 %0, %1, %2" : "=v"(wp[d2+0]) : "v"(p[o+0]), "v"(p[o+1]));
            asm("v_cvt_pk_bf16_f32 %0, %1, %2" : "=v"(wp[d2+1]) : "v"(p[o+2]), "v"(p[o+3]));
            asm("v_cvt_pk_bf16_f32 %0, %1, %2" : "=v"(wp[d2+2]) : "v"(p[o+4]), "v"(p[o+5]));
            asm("v_cvt_pk_bf16_f32 %0, %1, %2" : "=v"(wp[d2+3]) : "v"(p[o+6]), "v"(p[o+7]));
            asm("v_permlane32_swap_b32 %0, %1" : "+v"(wp[d2+0]), "+v"(wp[d2+2]));
            asm("v_permlane32_swap_b32 %0, %1" : "+v"(wp[d2+1]), "+v"(wp[d2+3]));
        }
        union { unsigned int u[4]; bf16x8 v; } pa0, pa1;
        pa0.u[0] = wp[0]; pa0.u[1] = wp[1]; pa0.u[2] = wp[2]; pa0.u[3] = wp[3];
        pa1.u[0] = wp[4]; pa1.u[1] = wp[5]; pa1.u[2] = wp[6]; pa1.u[3] = wp[7];
        __builtin_amdgcn_s_setprio(1);
#pragma unroll
        for (int ph = 0; ph < 2; ++ph) {
            const bf16x8 pv = ph ? pa1.v : pa0.v;
#pragma unroll
            for (int dt = 0; dt < 2; ++dt) {
                int d = dt * 32 + l31;
                int c = kt * 4 + ph * 2 + hs;
                int slot = c ^ (d & 7);
                bf16x8 vb = *reinterpret_cast<const bf16x8*>(VT + d * 128 + slot * 16);
                if (dt == 0) oacc0 = MFMA32(vb, pv, oacc0);
                else         oacc1 = MFMA32(vb, pv, oacc1);
            }
        }
        __builtin_amdgcn_s_setprio(0);
    };

    // ---- main loop: qt+1 tiles per half, lockstep barriers ----
    stage(0, half * 64);
    __syncthreads();
    for (int i = 0; i <= qt; ++i) {
        int k0 = (half + 2 * i) * 64;
        if (i < qt) stage((i + 1) & 1, (half + 2 * (i + 1)) * 64);
        const unsigned char* KH = smem + half * 32768 + (i & 1) * 16384;
        const unsigned char* VT = KH + 8192;

        bool skip0 = k0 > q_lo;          // subtile fully above diagonal
        bool skip1 = k0 + 32 > q_lo;
        bool diag0 = k0 == q_lo;
        bool diag1 = k0 + 32 == q_lo;
        if (!skip1) {                    // both subtiles live (2-deep pipeline)
            f32x16 s0 = qk(KH, 0);
            f32x16 s1 = qk(KH, 1);
            smpv(s0, VT, 0, diag0);
            smpv(s1, VT, 1, diag1);
        } else if (!skip0) {             // only subtile 0 (diag or last)
            f32x16 s0 = qk(KH, 0);
            smpv(s0, VT, 0, diag0);
        }
        __syncthreads();   // drains prefetch; guards dbuf reuse
    }

    // ---- merge the two K-halves in-LDS (layouts match reg-for-reg) ----
    if (half == 1) {
#pragma unroll
        for (int r = 0; r < 16; ++r) {
            MRG[(wq * 32 + r) * 64 + lane]      = oacc0[r];
            MRG[(wq * 32 + 16 + r) * 64 + lane] = oacc1[r];
        }
        if (hs == 0) {
            ML[(wq * 32 + l31) * 2]     = m;
            ML[(wq * 32 + l31) * 2 + 1] = lsum;
        }
    }
    __syncthreads();
    float inv = 0.f;
    if (half == 0) {
        float m1 = ML[(wq * 32 + l31) * 2];
        float l1 = ML[(wq * 32 + l31) * 2 + 1];
        float mm = fmaxf(m, m1);
        float w0 = __builtin_amdgcn_exp2f(m - mm);
        float w1 = __builtin_amdgcn_exp2f(m1 - mm);
        lsum = lsum * w0 + l1 * w1;
        inv = 1.f / lsum;
#pragma unroll
        for (int r = 0; r < 16; ++r) {
            oacc0[r] = oacc0[r] * w0 + MRG[(wq * 32 + r) * 64 + lane] * w1;
            oacc1[r] = oacc1[r] * w0 + MRG[(wq * 32 + 16 + r) * 64 + lane] * w1;
        }
    }
    __syncthreads();   // merge reads done before OT overwrite

    // ---- epilogue: normalize, stage OT[d][q], store attT bf16 ----
    if (half == 0) {
#pragma unroll
        for (int r = 0; r < 16; ++r) {
            int rowp = (r & 3) + 8 * (r >> 2) + 4 * hs;   // d-row within 32
            OT[(rowp)      * 132 + wq * 32 + l31] = oacc0[r] * inv;
            OT[(32 + rowp) * 132 + wq * 32 + l31] = oacc1[r] * inv;
        }
    }
    __syncthreads();
    {
        int d = tid >> 3, qb = tid & 7;   // 64 d x 8 groups of 16 q
        unsigned short tmp[16];
#pragma unroll
        for (int i = 0; i < 4; ++i) {
            f32x4 v = *reinterpret_cast<const f32x4*>(&OT[d * 132 + qb * 16 + i * 4]);
            tmp[i*4+0] = f2bf(v[0]); tmp[i*4+1] = f2bf(v[1]);
            tmp[i*4+2] = f2bf(v[2]); tmp[i*4+3] = f2bf(v[3]);
        }
        unsigned short* dst = attT + ((size_t)bh * 64 + d) * T_DIM + qt * 128 + qb * 16;
        *reinterpret_cast<u16x8*>(dst)     = *reinterpret_cast<u16x8*>(&tmp[0]);
        *reinterpret_cast<u16x8*>(dst + 8) = *reinterpret_cast<u16x8*>(&tmp[8]);
    }
}

// ---------------- Kernel 3: out = attT(as [4096][1024]) @ Wr^T + br ----------
// BM=128, BN=64, BK=64, 4 waves; gload_lds staging (xor-swizzled), dbuf
// prefetch; MFMA32; wave w owns rows [32w,32w+32).
__global__ __launch_bounds__(256) void final_gemm_mfma(
    const unsigned short* __restrict__ A, const unsigned short* __restrict__ Bw,
    const float* __restrict__ br, float* __restrict__ out)
{
    __shared__ __align__(16) unsigned char gsm[49152];   // 2 x (A 16KB + B 8KB)
    int nt = blockIdx.x;   // 16 tiles over N=1024
    int mt = blockIdx.y;   // 32 tiles over M=4096
    int tid = threadIdx.x;
    int w = tid >> 6;
    int lane = tid & 63;
    int l31 = lane & 31, hs = lane >> 5;
    int srow = lane >> 3, scol = lane & 7;

    auto stage = [&](int bs, int kt) {
        unsigned char* As = gsm + bs * 24576;
        unsigned char* Bs = As + 16384;
#pragma unroll
        for (int i = 0; i < 4; ++i) {
            int row = i * 32 + w * 8 + srow;
            gload16(A + (size_t)(mt * 128 + row) * 1024 + kt * 64 + ((scol ^ (row & 7)) * 8),
                    As + i * 4096 + w * 1024 + lane * 16);
        }
#pragma unroll
        for (int i = 0; i < 2; ++i) {
            int row = i * 32 + w * 8 + srow;
            gload16(Bw + (size_t)(nt * 64 + row) * 1024 + kt * 64 + ((scol ^ (row & 7)) * 8),
                    Bs + i * 4096 + w * 1024 + lane * 16);
        }
    };

    f32x16 oa0 = zero16(), oa1 = zero16();
    stage(0, 0);
    __syncthreads();
    for (int kt = 0; kt < 16; ++kt) {
        if (kt < 15) stage((kt + 1) & 1, kt + 1);
        const unsigned char* As = gsm + (kt & 1) * 24576;
        const unsigned char* Bs = As + 16384;
        int arow = w * 32 + l31;
        __builtin_amdgcn_s_setprio(1);
#pragma unroll
        for (int st = 0; st < 4; ++st) {
            int c = st * 2 + hs;
            bf16x8 af = *reinterpret_cast<const bf16x8*>(As + arow * 128 + ((c ^ (arow & 7)) * 16));
            {
                bf16x8 bf0 = *reinterpret_cast<const bf16x8*>(Bs + l31 * 128 + ((c ^ (l31 & 7)) * 16));
                oa0 = MFMA32(af, bf0, oa0);
            }
            {
                int brow = 32 + l31;
                bf16x8 bf1 = *reinterpret_cast<const bf16x8*>(Bs + brow * 128 + ((c ^ (brow & 7)) * 16));
                oa1 = MFMA32(af, bf1, oa1);
            }
        }
        __builtin_amdgcn_s_setprio(0);
        __syncthreads();
    }

#pragma unroll
    for (int ng = 0; ng < 2; ++ng) {
        int col = nt * 64 + ng * 32 + l31;
        float bias = br[col];
        const f32x16& oa = ng ? oa1 : oa0;
#pragma unroll
        for (int r = 0; r < 16; ++r) {
            int rowp = (r & 3) + 8 * (r >> 2) + 4 * hs;
            int row = mt * 128 + w * 32 + rowp;
            out[(size_t)row * 1024 + col] = oa[r] + bias;
        }
    }
}

extern "C" void kernel_launch(void* const* d_in, const int* in_sizes, int n_in,
                              void* d_out, int out_size, void* d_ws, size_t ws_size,
                              hipStream_t stream) {
    const float* x  = (const float*)d_in[0];
    const float* Wq = (const float*)d_in[1];
    const float* Wk = (const float*)d_in[2];
    const float* Wv = (const float*)d_in[3];
    const float* Er = (const float*)d_in[4];
    const float* Wr = (const float*)d_in[5];
    const float* br = (const float*)d_in[6];
    float* out = (float*)d_out;

    const size_t nQ = (size_t)B_DIM * H_DIM * T_DIM * S_DIM;   // 4,194,304
    char* p = (char*)d_ws;
    unsigned short* qb = (unsigned short*)p;   p += nQ * 2;
    unsigned short* kh = (unsigned short*)p;   p += nQ * 2;
    unsigned short* vT = (unsigned short*)p;   p += nQ * 2;
    unsigned short* attT = (unsigned short*)p; p += nQ * 2;
    unsigned short* wrb = (unsigned short*)p;  p += (size_t)E_DIM * E_DIM * 2;
    unsigned short* whb = (unsigned short*)p;  p += (size_t)3 * 65536 * 2;
    size_t need = (size_t)(p - (char*)d_ws);
    if (ws_size < need) {
        fprintf(stderr, "WS TOO SMALL: have %zu need %zu\n", ws_size, need);
        return;
    }

    prep_w<<<1216, 256, 0, stream>>>(Wq, Wk, Wv, Wr, whb, wrb);
    qkv_mfma<<<4096, 64, 0, stream>>>(x, whb, Er, qb, kh, vT);
    attn_mfma32<<<512, 512, 0, stream>>>(qb, kh, vT, attT);
    final_gemm_mfma<<<dim3(16, 32), 256, 0, stream>>>(attT, wrb, br, out);
}